// Round 2
// baseline (1336.061 us; speedup 1.0000x reference)
//
#include <hip/hip_runtime.h>
#include <stdint.h>

typedef __attribute__((ext_vector_type(8))) short short8;
typedef __attribute__((ext_vector_type(8))) unsigned short ushort8;
typedef __attribute__((ext_vector_type(4))) float f32x4;

#define SEQ     2048
#define HIDDIM  4096
#define NHEAD   32
#define HEADD   128
#define ROPED   64
#define QRANK   1536
#define KVRANK  896
#define DQK     192          // ROPED + HEADD
#define KVPAD   1024         // padded (KVRANK+ROPED)=960 -> 1024
#define QDIM    6144         // NHEAD*DQK
#define KVUPD   8192         // NHEAD*2*HEADD
#define RMS_EPS 1e-6f
#define ATT_SCALE 0.07216878364870322f  // 192^-0.5

static __device__ __forceinline__ uint16_t f32_to_bf16(float f) {
  union { float f; uint32_t u; } v; v.f = f;
  uint32_t u = v.u;
  u += 0x7FFFu + ((u >> 16) & 1u);   // round-to-nearest-even
  return (uint16_t)(u >> 16);
}
static __device__ __forceinline__ float bf16_to_f32(uint16_t h) {
  union { uint32_t u; float f; } v; v.u = ((uint32_t)h) << 16;
  return v.f;
}

// ---------------- convert x: fp32 -> bf16 ----------------
__global__ void conv_f32_bf16(const float* __restrict__ in, uint16_t* __restrict__ out, size_t n) {
  size_t i = blockIdx.x * (size_t)blockDim.x + threadIdx.x;
  size_t stride = (size_t)gridDim.x * blockDim.x;
  for (; i < n; i += stride) out[i] = f32_to_bf16(in[i]);
}

// ---------------- RMSNorm (bf16 in -> bf16 out) ----------------
__global__ void rmsnorm_bf16(const uint16_t* __restrict__ in, const float* __restrict__ w,
                             uint16_t* __restrict__ out, int C, int ldin) {
  int s = blockIdx.x;
  const uint16_t* row = in + (size_t)s * ldin;
  float ss = 0.f;
  for (int c = threadIdx.x; c < C; c += blockDim.x) { float v = bf16_to_f32(row[c]); ss += v * v; }
#pragma unroll
  for (int off = 32; off > 0; off >>= 1) ss += __shfl_down(ss, off, 64);
  __shared__ float red[4];
  int wid = threadIdx.x >> 6;
  if ((threadIdx.x & 63) == 0) red[wid] = ss;
  __syncthreads();
  float total = red[0] + red[1] + red[2] + red[3];
  float scale = rsqrtf(total / (float)C + RMS_EPS);
  for (int c = threadIdx.x; c < C; c += blockDim.x)
    out[(size_t)s * C + c] = f32_to_bf16(bf16_to_f32(row[c]) * scale * w[c]);
}

// ---------------- GEMM: C(M,Npad) = A(M,K) bf16 @ B(Nreal,K)^T fp32 ----------------
// B is converted fp32->bf16 during LDS staging; rows >= Nreal are zero.
// M%128==0, Npad%128==0, K%32==0. 256 threads, 128x128 tile, BK=32.
template <typename CT>
__global__ __launch_bounds__(256) void gemm_bt(const uint16_t* __restrict__ A,
                                               const float* __restrict__ B,
                                               CT* __restrict__ C,
                                               int M, int Npad, int Nreal, int K) {
  __shared__ __align__(16) uint16_t As[128 * 32];
  __shared__ __align__(16) uint16_t Bs[128 * 32];
  const int t = threadIdx.x;
  const int m0 = blockIdx.y * 128, n0 = blockIdx.x * 128;
  const int w = t >> 6, l = t & 63;
  const int rb = (w >> 1) * 64, cb = (w & 1) * 64;
  const int g = l >> 4, lm = l & 15;
  const int arow = t >> 2;            // 0..63
  const int acol = (t & 3) * 8;       // 0,8,16,24
  const int brow0 = n0 + arow, brow1 = n0 + 64 + arow;

  f32x4 acc[4][4];
#pragma unroll
  for (int i = 0; i < 4; ++i)
#pragma unroll
    for (int j = 0; j < 4; ++j) acc[i][j] = (f32x4){0.f, 0.f, 0.f, 0.f};

  for (int k0 = 0; k0 < K; k0 += 32) {
    __syncthreads();
    uint4 va0 = *(const uint4*)(A + (size_t)(m0 + arow) * K + k0 + acol);
    uint4 va1 = *(const uint4*)(A + (size_t)(m0 + 64 + arow) * K + k0 + acol);
    float4 b0a = {0,0,0,0}, b0b = {0,0,0,0}, b1a = {0,0,0,0}, b1b = {0,0,0,0};
    if (brow0 < Nreal) {
      const float* p = B + (size_t)brow0 * K + k0 + acol;
      b0a = *(const float4*)p; b0b = *(const float4*)(p + 4);
    }
    if (brow1 < Nreal) {
      const float* p = B + (size_t)brow1 * K + k0 + acol;
      b1a = *(const float4*)p; b1b = *(const float4*)(p + 4);
    }
    ushort8 bb0, bb1;
    bb0[0] = f32_to_bf16(b0a.x); bb0[1] = f32_to_bf16(b0a.y);
    bb0[2] = f32_to_bf16(b0a.z); bb0[3] = f32_to_bf16(b0a.w);
    bb0[4] = f32_to_bf16(b0b.x); bb0[5] = f32_to_bf16(b0b.y);
    bb0[6] = f32_to_bf16(b0b.z); bb0[7] = f32_to_bf16(b0b.w);
    bb1[0] = f32_to_bf16(b1a.x); bb1[1] = f32_to_bf16(b1a.y);
    bb1[2] = f32_to_bf16(b1a.z); bb1[3] = f32_to_bf16(b1a.w);
    bb1[4] = f32_to_bf16(b1b.x); bb1[5] = f32_to_bf16(b1b.y);
    bb1[6] = f32_to_bf16(b1b.z); bb1[7] = f32_to_bf16(b1b.w);
    ((uint4*)As)[t] = va0;
    ((uint4*)As)[256 + t] = va1;
    ((ushort8*)Bs)[t] = bb0;
    ((ushort8*)Bs)[256 + t] = bb1;
    __syncthreads();
    short8 af[4], bfr[4];
#pragma unroll
    for (int i = 0; i < 4; ++i)
      af[i] = *(const short8*)(As + (rb + i * 16 + lm) * 32 + g * 8);
#pragma unroll
    for (int j = 0; j < 4; ++j)
      bfr[j] = *(const short8*)(Bs + (cb + j * 16 + lm) * 32 + g * 8);
#pragma unroll
    for (int i = 0; i < 4; ++i)
#pragma unroll
      for (int j = 0; j < 4; ++j)
        acc[i][j] = __builtin_amdgcn_mfma_f32_16x16x32_bf16(af[i], bfr[j], acc[i][j], 0, 0, 0);
  }

#pragma unroll
  for (int i = 0; i < 4; ++i)
#pragma unroll
    for (int j = 0; j < 4; ++j)
#pragma unroll
      for (int r = 0; r < 4; ++r) {
        int row = m0 + rb + i * 16 + g * 4 + r;
        int col = n0 + cb + j * 16 + lm;
        float v = acc[i][j][r];
        if constexpr (sizeof(CT) == 4) C[(size_t)row * Npad + col] = v;
        else                           C[(size_t)row * Npad + col] = (CT)f32_to_bf16(v);
      }
}

// ---------------- build q_full[h][s][192] (rope + scale, bf16) ----------------
__global__ void build_q_kernel(const uint16_t* __restrict__ qraw, const float* __restrict__ cosT,
                               const float* __restrict__ sinT, uint16_t* __restrict__ qf) {
  int s = blockIdx.x, h = blockIdx.y, d = threadIdx.x;  // d in [0,192)
  const uint16_t* base = qraw + (size_t)s * QDIM + h * DQK;
  float val;
  if (d < ROPED) {
    float c = cosT[s * ROPED + d], sn = sinT[s * ROPED + d];
    float x = bf16_to_f32(base[d]);
    float other = (d < 32) ? -bf16_to_f32(base[d + 32]) : bf16_to_f32(base[d - 32]);
    val = x * c + other * sn;
  } else {
    val = bf16_to_f32(base[d]);
  }
  qf[((size_t)(h * SEQ + s)) * DQK + d] = f32_to_bf16(val * ATT_SCALE);
}

// ---------------- build k_full[h][s][192] (rope on shared k_rope, bf16) ----------------
__global__ void build_k_kernel(const uint16_t* __restrict__ kvraw, const uint16_t* __restrict__ kvup,
                               const float* __restrict__ cosT, const float* __restrict__ sinT,
                               uint16_t* __restrict__ kf) {
  int s = blockIdx.x, h = blockIdx.y, d = threadIdx.x;
  float val;
  if (d < ROPED) {
    float c = cosT[s * ROPED + d], sn = sinT[s * ROPED + d];
    const uint16_t* base = kvraw + (size_t)s * KVPAD + KVRANK;  // cols 896..959
    float x = bf16_to_f32(base[d]);
    float other = (d < 32) ? -bf16_to_f32(base[d + 32]) : bf16_to_f32(base[d - 32]);
    val = x * c + other * sn;
  } else {
    val = bf16_to_f32(kvup[(size_t)s * KVUPD + h * 256 + (d - ROPED)]);
  }
  kf[((size_t)(h * SEQ + s)) * DQK + d] = f32_to_bf16(val);
}

// ---------------- build v[h][s][128] bf16 ----------------
__global__ void build_v_kernel(const uint16_t* __restrict__ kvup, uint16_t* __restrict__ vf) {
  int s = blockIdx.x, h = blockIdx.y, d = threadIdx.x;  // d in [0,128)
  vf[((size_t)(h * SEQ + s)) * HEADD + d] = kvup[(size_t)s * KVUPD + h * 256 + HEADD + d];
}

// ---------------- flash attention ----------------
// grid (SEQ/64, NHEAD), 256 threads = 4 waves; wave w handles q rows m0+16w..+15.
__global__ __launch_bounds__(256) void attn_kernel(const uint16_t* __restrict__ qf,
                                                   const uint16_t* __restrict__ kf,
                                                   const uint16_t* __restrict__ vf,
                                                   uint16_t* __restrict__ attn_out) {
  const int h = blockIdx.y;
  const int m0 = blockIdx.x * 64;
  const int w = threadIdx.x >> 6;
  const int l = threadIdx.x & 63;
  const int g = l >> 4, lm = l & 15;
  const int mw = m0 + w * 16;

  __shared__ __align__(16) uint16_t Plds[4 * 512];
  uint16_t* Pw = Plds + w * 512;  // 16 rows x 32 cols bf16

  // Q fragments (scale already folded in)
  const uint16_t* qrow = qf + ((size_t)(h * SEQ + mw + lm)) * DQK;
  short8 aq[6];
#pragma unroll
  for (int c = 0; c < 6; ++c) aq[c] = *(const short8*)(qrow + c * 32 + g * 8);

  f32x4 o[8];
#pragma unroll
  for (int dc = 0; dc < 8; ++dc) o[dc] = (f32x4){0.f, 0.f, 0.f, 0.f};
  float m_r[4], l_r[4];
#pragma unroll
  for (int r = 0; r < 4; ++r) { m_r[r] = -INFINITY; l_r[r] = 0.f; }

  for (int n0 = 0; n0 < mw + 16; n0 += 32) {
    // S tile: 16 q-rows x 32 keys
    f32x4 s0 = (f32x4){0.f, 0.f, 0.f, 0.f};
    f32x4 s1 = (f32x4){0.f, 0.f, 0.f, 0.f};
    {
      const uint16_t* k0p = kf + ((size_t)(h * SEQ + n0 + lm)) * DQK + g * 8;
      const uint16_t* k1p = kf + ((size_t)(h * SEQ + n0 + 16 + lm)) * DQK + g * 8;
#pragma unroll
      for (int c = 0; c < 6; ++c) {
        short8 bk0 = *(const short8*)(k0p + c * 32);
        short8 bk1 = *(const short8*)(k1p + c * 32);
        s0 = __builtin_amdgcn_mfma_f32_16x16x32_bf16(aq[c], bk0, s0, 0, 0, 0);
        s1 = __builtin_amdgcn_mfma_f32_16x16x32_bf16(aq[c], bk1, s1, 0, 0, 0);
      }
    }
    // online softmax per row (rows g*4+r, cols lm and lm+16)
    float alpha_r[4];
#pragma unroll
    for (int r = 0; r < 4; ++r) {
      int row = mw + g * 4 + r;
      float v0 = ((n0 + lm) <= row) ? s0[r] : -1e30f;
      float v1 = ((n0 + 16 + lm) <= row) ? s1[r] : -1e30f;
      float mx = fmaxf(v0, v1);
#pragma unroll
      for (int off = 8; off > 0; off >>= 1) mx = fmaxf(mx, __shfl_xor(mx, off, 16));
      float mnew = fmaxf(m_r[r], mx);
      float alpha = __expf(m_r[r] - mnew);
      float p0 = __expf(v0 - mnew);
      float p1 = __expf(v1 - mnew);
      float rs = p0 + p1;
#pragma unroll
      for (int off = 8; off > 0; off >>= 1) rs += __shfl_xor(rs, off, 16);
      l_r[r] = l_r[r] * alpha + rs;
      m_r[r] = mnew;
      alpha_r[r] = alpha;
      Pw[(g * 4 + r) * 32 + lm] = f32_to_bf16(p0);
      Pw[(g * 4 + r) * 32 + 16 + lm] = f32_to_bf16(p1);
    }
#pragma unroll
    for (int dc = 0; dc < 8; ++dc)
#pragma unroll
      for (int r = 0; r < 4; ++r) o[dc][r] *= alpha_r[r];

    // wave-local LDS fence: writes above -> reads below (wave is lockstep)
    asm volatile("s_waitcnt lgkmcnt(0)" ::: "memory");

    // P (A-layout) from LDS
    short8 ap = *(const short8*)(Pw + lm * 32 + g * 8);
    // O += P @ V
#pragma unroll
    for (int dc = 0; dc < 8; ++dc) {
      short8 bv;
#pragma unroll
      for (int j = 0; j < 8; ++j)
        bv[j] = (short)vf[((size_t)(h * SEQ + n0 + g * 8 + j)) * HEADD + dc * 16 + lm];
      o[dc] = __builtin_amdgcn_mfma_f32_16x16x32_bf16(ap, bv, o[dc], 0, 0, 0);
    }
  }

#pragma unroll
  for (int dc = 0; dc < 8; ++dc)
#pragma unroll
    for (int r = 0; r < 4; ++r) {
      float val = o[dc][r] / l_r[r];
      attn_out[(size_t)(mw + g * 4 + r) * (NHEAD * HEADD) + h * HEADD + dc * 16 + lm] =
          f32_to_bf16(val);
    }
}

// ---------------- launch ----------------
extern "C" void kernel_launch(void* const* d_in, const int* in_sizes, int n_in,
                              void* d_out, int out_size, void* d_ws, size_t ws_size,
                              hipStream_t stream) {
  const float* x       = (const float*)d_in[0];
  const float* cosT    = (const float*)d_in[1];
  const float* sinT    = (const float*)d_in[2];
  const float* q_a_w   = (const float*)d_in[3];
  const float* q_a_nw  = (const float*)d_in[4];
  const float* q_b_w   = (const float*)d_in[5];
  const float* kv_a_w  = (const float*)d_in[6];
  const float* kv_a_nw = (const float*)d_in[7];
  const float* kv_b_w  = (const float*)d_in[8];
  const float* o_w     = (const float*)d_in[9];
  float* out = (float*)d_out;
  (void)in_sizes; (void)n_in; (void)out_size; (void)ws_size;

  // Workspace plan (~138 MB total):
  char* base = (char*)d_ws;
  size_t off = 0;
  auto alloc = [&](size_t bytes) -> void* {
    void* r = base + off;
    off += (bytes + 255) & ~(size_t)255;
    return r;
  };
  uint16_t* x_bf      = (uint16_t*)alloc((size_t)SEQ * HIDDIM * 2);   // later reused: attn_bf (same size)
  uint16_t* kv_raw    = (uint16_t*)alloc((size_t)SEQ * KVPAD * 2);
  uint16_t* kv_lat_bf = (uint16_t*)alloc((size_t)SEQ * KVRANK * 2);
  uint16_t* big       = (uint16_t*)alloc((size_t)SEQ * KVUPD * 2);    // kv_up_bf, later q_raw
  uint16_t* q_a_out   = (uint16_t*)alloc((size_t)SEQ * QRANK * 2);
  uint16_t* q_lat_bf  = (uint16_t*)alloc((size_t)SEQ * QRANK * 2);
  uint16_t* q_full    = (uint16_t*)alloc((size_t)NHEAD * SEQ * DQK * 2);
  uint16_t* k_full    = (uint16_t*)alloc((size_t)NHEAD * SEQ * DQK * 2);
  uint16_t* v_bf      = (uint16_t*)alloc((size_t)NHEAD * SEQ * HEADD * 2);
  uint16_t* attn_bf   = x_bf;  // alias: x_bf dead after q_a gemm

  // x -> bf16
  conv_f32_bf16<<<2048, 256, 0, stream>>>(x, x_bf, (size_t)SEQ * HIDDIM);

  // kv path
  gemm_bt<uint16_t><<<dim3(KVPAD / 128, SEQ / 128), 256, 0, stream>>>(
      x_bf, kv_a_w, kv_raw, SEQ, KVPAD, KVRANK + ROPED, HIDDIM);
  rmsnorm_bf16<<<SEQ, 256, 0, stream>>>(kv_raw, kv_a_nw, kv_lat_bf, KVRANK, KVPAD);
  gemm_bt<uint16_t><<<dim3(KVUPD / 128, SEQ / 128), 256, 0, stream>>>(
      kv_lat_bf, kv_b_w, big, SEQ, KVUPD, KVUPD, KVRANK);
  build_k_kernel<<<dim3(SEQ, NHEAD), DQK, 0, stream>>>(kv_raw, big, cosT, sinT, k_full);
  build_v_kernel<<<dim3(SEQ, NHEAD), HEADD, 0, stream>>>(big, v_bf);

  // q path
  gemm_bt<uint16_t><<<dim3(QRANK / 128, SEQ / 128), 256, 0, stream>>>(
      x_bf, q_a_w, q_a_out, SEQ, QRANK, QRANK, HIDDIM);
  rmsnorm_bf16<<<SEQ, 256, 0, stream>>>(q_a_out, q_a_nw, q_lat_bf, QRANK, QRANK);
  gemm_bt<uint16_t><<<dim3(QDIM / 128, SEQ / 128), 256, 0, stream>>>(
      q_lat_bf, q_b_w, big, SEQ, QDIM, QDIM, QRANK);   // big reused as q_raw
  build_q_kernel<<<dim3(SEQ, NHEAD), DQK, 0, stream>>>(big, cosT, sinT, q_full);

  // attention (writes attn_bf == x_bf region; x_bf no longer needed)
  attn_kernel<<<dim3(SEQ / 64, NHEAD), 256, 0, stream>>>(q_full, k_full, v_bf, attn_bf);

  // output projection -> d_out (fp32)
  gemm_bt<float><<<dim3(HIDDIM / 128, SEQ / 128), 256, 0, stream>>>(
      attn_bf, o_w, out, SEQ, HIDDIM, HIDDIM, HIDDIM);
}

// Round 3
// 1188.294 us; speedup vs baseline: 1.1244x; 1.1244x over previous
//
#include <hip/hip_runtime.h>
#include <stdint.h>

typedef __attribute__((ext_vector_type(8))) short short8;
typedef __attribute__((ext_vector_type(8))) unsigned short ushort8;
typedef __attribute__((ext_vector_type(4))) float f32x4;

#define SEQ     2048
#define HIDDIM  4096
#define NHEAD   32
#define HEADD   128
#define ROPED   64
#define QRANK   1536
#define KVRANK  896
#define DQK     192          // ROPED + HEADD
#define KVPAD   1024         // padded (KVRANK+ROPED)=960 -> 1024
#define QDIM    6144         // NHEAD*DQK
#define KVUPD   8192         // NHEAD*2*HEADD
#define RMS_EPS 1e-6f
#define ATT_SCALE 0.07216878364870322f  // 192^-0.5

static __device__ __forceinline__ uint16_t f32_to_bf16(float f) {
  union { float f; uint32_t u; } v; v.f = f;
  uint32_t u = v.u;
  u += 0x7FFFu + ((u >> 16) & 1u);   // round-to-nearest-even
  return (uint16_t)(u >> 16);
}
static __device__ __forceinline__ float bf16_to_f32(uint16_t h) {
  union { uint32_t u; float f; } v; v.u = ((uint32_t)h) << 16;
  return v.f;
}

// ---------------- convert x: fp32 -> bf16 ----------------
__global__ void conv_f32_bf16(const float* __restrict__ in, uint16_t* __restrict__ out, size_t n) {
  size_t i = blockIdx.x * (size_t)blockDim.x + threadIdx.x;
  size_t stride = (size_t)gridDim.x * blockDim.x;
  for (; i < n; i += stride) out[i] = f32_to_bf16(in[i]);
}

// ---------------- RMSNorm (bf16 in -> bf16 out) ----------------
__global__ void rmsnorm_bf16(const uint16_t* __restrict__ in, const float* __restrict__ w,
                             uint16_t* __restrict__ out, int C, int ldin) {
  int s = blockIdx.x;
  const uint16_t* row = in + (size_t)s * ldin;
  float ss = 0.f;
  for (int c = threadIdx.x; c < C; c += blockDim.x) { float v = bf16_to_f32(row[c]); ss += v * v; }
#pragma unroll
  for (int off = 32; off > 0; off >>= 1) ss += __shfl_down(ss, off, 64);
  __shared__ float red[4];
  int wid = threadIdx.x >> 6;
  if ((threadIdx.x & 63) == 0) red[wid] = ss;
  __syncthreads();
  float total = red[0] + red[1] + red[2] + red[3];
  float scale = rsqrtf(total / (float)C + RMS_EPS);
  for (int c = threadIdx.x; c < C; c += blockDim.x)
    out[(size_t)s * C + c] = f32_to_bf16(bf16_to_f32(row[c]) * scale * w[c]);
}

// ---------------- GEMM: C(M,Npad) = A(M,K) bf16 @ B(Nreal,K)^T fp32 ----------------
template <typename CT>
__global__ __launch_bounds__(256) void gemm_bt(const uint16_t* __restrict__ A,
                                               const float* __restrict__ B,
                                               CT* __restrict__ C,
                                               int M, int Npad, int Nreal, int K) {
  __shared__ __align__(16) uint16_t As[128 * 32];
  __shared__ __align__(16) uint16_t Bs[128 * 32];
  const int t = threadIdx.x;
  const int m0 = blockIdx.y * 128, n0 = blockIdx.x * 128;
  const int w = t >> 6, l = t & 63;
  const int rb = (w >> 1) * 64, cb = (w & 1) * 64;
  const int g = l >> 4, lm = l & 15;
  const int arow = t >> 2;            // 0..63
  const int acol = (t & 3) * 8;       // 0,8,16,24
  const int brow0 = n0 + arow, brow1 = n0 + 64 + arow;

  f32x4 acc[4][4];
#pragma unroll
  for (int i = 0; i < 4; ++i)
#pragma unroll
    for (int j = 0; j < 4; ++j) acc[i][j] = (f32x4){0.f, 0.f, 0.f, 0.f};

  for (int k0 = 0; k0 < K; k0 += 32) {
    __syncthreads();
    uint4 va0 = *(const uint4*)(A + (size_t)(m0 + arow) * K + k0 + acol);
    uint4 va1 = *(const uint4*)(A + (size_t)(m0 + 64 + arow) * K + k0 + acol);
    float4 b0a = {0,0,0,0}, b0b = {0,0,0,0}, b1a = {0,0,0,0}, b1b = {0,0,0,0};
    if (brow0 < Nreal) {
      const float* p = B + (size_t)brow0 * K + k0 + acol;
      b0a = *(const float4*)p; b0b = *(const float4*)(p + 4);
    }
    if (brow1 < Nreal) {
      const float* p = B + (size_t)brow1 * K + k0 + acol;
      b1a = *(const float4*)p; b1b = *(const float4*)(p + 4);
    }
    ushort8 bb0, bb1;
    bb0[0] = f32_to_bf16(b0a.x); bb0[1] = f32_to_bf16(b0a.y);
    bb0[2] = f32_to_bf16(b0a.z); bb0[3] = f32_to_bf16(b0a.w);
    bb0[4] = f32_to_bf16(b0b.x); bb0[5] = f32_to_bf16(b0b.y);
    bb0[6] = f32_to_bf16(b0b.z); bb0[7] = f32_to_bf16(b0b.w);
    bb1[0] = f32_to_bf16(b1a.x); bb1[1] = f32_to_bf16(b1a.y);
    bb1[2] = f32_to_bf16(b1a.z); bb1[3] = f32_to_bf16(b1a.w);
    bb1[4] = f32_to_bf16(b1b.x); bb1[5] = f32_to_bf16(b1b.y);
    bb1[6] = f32_to_bf16(b1b.z); bb1[7] = f32_to_bf16(b1b.w);
    ((uint4*)As)[t] = va0;
    ((uint4*)As)[256 + t] = va1;
    ((ushort8*)Bs)[t] = bb0;
    ((ushort8*)Bs)[256 + t] = bb1;
    __syncthreads();
    short8 af[4], bfr[4];
#pragma unroll
    for (int i = 0; i < 4; ++i)
      af[i] = *(const short8*)(As + (rb + i * 16 + lm) * 32 + g * 8);
#pragma unroll
    for (int j = 0; j < 4; ++j)
      bfr[j] = *(const short8*)(Bs + (cb + j * 16 + lm) * 32 + g * 8);
#pragma unroll
    for (int i = 0; i < 4; ++i)
#pragma unroll
      for (int j = 0; j < 4; ++j)
        acc[i][j] = __builtin_amdgcn_mfma_f32_16x16x32_bf16(af[i], bfr[j], acc[i][j], 0, 0, 0);
  }

#pragma unroll
  for (int i = 0; i < 4; ++i)
#pragma unroll
    for (int j = 0; j < 4; ++j)
#pragma unroll
      for (int r = 0; r < 4; ++r) {
        int row = m0 + rb + i * 16 + g * 4 + r;
        int col = n0 + cb + j * 16 + lm;
        float v = acc[i][j][r];
        if constexpr (sizeof(CT) == 4) C[(size_t)row * Npad + col] = v;
        else                           C[(size_t)row * Npad + col] = (CT)f32_to_bf16(v);
      }
}

// ---------------- build q_full[h][s][192] (rope + scale, bf16) ----------------
__global__ void build_q_kernel(const uint16_t* __restrict__ qraw, const float* __restrict__ cosT,
                               const float* __restrict__ sinT, uint16_t* __restrict__ qf) {
  int s = blockIdx.x, h = blockIdx.y, d = threadIdx.x;  // d in [0,192)
  const uint16_t* base = qraw + (size_t)s * QDIM + h * DQK;
  float val;
  if (d < ROPED) {
    float c = cosT[s * ROPED + d], sn = sinT[s * ROPED + d];
    float x = bf16_to_f32(base[d]);
    float other = (d < 32) ? -bf16_to_f32(base[d + 32]) : bf16_to_f32(base[d - 32]);
    val = x * c + other * sn;
  } else {
    val = bf16_to_f32(base[d]);
  }
  qf[((size_t)(h * SEQ + s)) * DQK + d] = f32_to_bf16(val * ATT_SCALE);
}

// ---------------- build k_full[h][s][192] (rope on shared k_rope, bf16) ----------------
__global__ void build_k_kernel(const uint16_t* __restrict__ kvraw, const uint16_t* __restrict__ kvup,
                               const float* __restrict__ cosT, const float* __restrict__ sinT,
                               uint16_t* __restrict__ kf) {
  int s = blockIdx.x, h = blockIdx.y, d = threadIdx.x;
  float val;
  if (d < ROPED) {
    float c = cosT[s * ROPED + d], sn = sinT[s * ROPED + d];
    const uint16_t* base = kvraw + (size_t)s * KVPAD + KVRANK;  // cols 896..959
    float x = bf16_to_f32(base[d]);
    float other = (d < 32) ? -bf16_to_f32(base[d + 32]) : bf16_to_f32(base[d - 32]);
    val = x * c + other * sn;
  } else {
    val = bf16_to_f32(kvup[(size_t)s * KVUPD + h * 256 + (d - ROPED)]);
  }
  kf[((size_t)(h * SEQ + s)) * DQK + d] = f32_to_bf16(val);
}

// ---------------- transpose V: kvup[s][h*256+128+d] -> vt[h][d][s] ----------------
// grid (SEQ/64, NHEAD), 256 threads. LDS tile 64 s x 128 d.
__global__ __launch_bounds__(256) void transpose_v(const uint16_t* __restrict__ kvup,
                                                   uint16_t* __restrict__ vt) {
  __shared__ uint16_t tile[64][136];
  const int s0 = blockIdx.x * 64, h = blockIdx.y, t = threadIdx.x;
  {
    int sl = t >> 2;          // 0..63
    int dch = (t & 3) * 32;   // 0,32,64,96
    const uint16_t* src = kvup + (size_t)(s0 + sl) * KVUPD + h * 256 + HEADD + dch;
#pragma unroll
    for (int j = 0; j < 32; j += 8)
      *(ushort8*)&tile[sl][dch + j] = *(const ushort8*)(src + j);
  }
  __syncthreads();
  {
    int d = t >> 1;           // 0..127
    int sch = (t & 1) * 32;   // 0, 32
    uint16_t buf[32];
#pragma unroll
    for (int j = 0; j < 32; ++j) buf[j] = tile[sch + j][d];
    uint16_t* dst = vt + ((size_t)(h * HEADD) + d) * SEQ + s0 + sch;
#pragma unroll
    for (int j = 0; j < 32; j += 8) *(ushort8*)(dst + j) = *(ushort8*)(buf + j);
  }
}

// ---------------- flash attention ----------------
// grid (SEQ/128, NHEAD), 256 threads = 4 waves, 32 q-rows per wave.
// Causal balance: waves 0,1 take chunk bx, waves 2,3 take chunk (31-bx) (64-row chunks).
__global__ __launch_bounds__(256) void attn_kernel(const uint16_t* __restrict__ qf,
                                                   const uint16_t* __restrict__ kf,
                                                   const uint16_t* __restrict__ vt,
                                                   uint16_t* __restrict__ attn_out) {
  const int h = blockIdx.y;
  const int w = threadIdx.x >> 6;
  const int l = threadIdx.x & 63;
  const int g = l >> 4, lm = l & 15;
  const int chunk = (w < 2) ? blockIdx.x : (31 - blockIdx.x);
  const int mw = chunk * 64 + (w & 1) * 32;   // first of this wave's 32 q-rows

  __shared__ __align__(16) uint16_t Plds[4 * 1024];
  uint16_t* Pw = Plds + w * 1024;  // 32 rows x 32 cols bf16

  // Q fragments for two row-sets (scale already folded in)
  const uint16_t* q0 = qf + ((size_t)(h * SEQ + mw + lm)) * DQK;
  const uint16_t* q1 = qf + ((size_t)(h * SEQ + mw + 16 + lm)) * DQK;
  short8 aq0[6], aq1[6];
#pragma unroll
  for (int c = 0; c < 6; ++c) {
    aq0[c] = *(const short8*)(q0 + c * 32 + g * 8);
    aq1[c] = *(const short8*)(q1 + c * 32 + g * 8);
  }

  f32x4 o0[8], o1[8];
#pragma unroll
  for (int dc = 0; dc < 8; ++dc) { o0[dc] = (f32x4){0,0,0,0}; o1[dc] = (f32x4){0,0,0,0}; }
  float m0r[4], l0r[4], m1r[4], l1r[4];
#pragma unroll
  for (int r = 0; r < 4; ++r) { m0r[r] = -INFINITY; l0r[r] = 0.f; m1r[r] = -INFINITY; l1r[r] = 0.f; }

  for (int n0 = 0; n0 < mw + 32; n0 += 32) {
    f32x4 s00 = (f32x4){0,0,0,0}, s01 = (f32x4){0,0,0,0};
    f32x4 s10 = (f32x4){0,0,0,0}, s11 = (f32x4){0,0,0,0};
    {
      const uint16_t* k0p = kf + ((size_t)(h * SEQ + n0 + lm)) * DQK + g * 8;
      const uint16_t* k1p = kf + ((size_t)(h * SEQ + n0 + 16 + lm)) * DQK + g * 8;
#pragma unroll
      for (int c = 0; c < 6; ++c) {
        short8 bk0 = *(const short8*)(k0p + c * 32);
        short8 bk1 = *(const short8*)(k1p + c * 32);
        s00 = __builtin_amdgcn_mfma_f32_16x16x32_bf16(aq0[c], bk0, s00, 0, 0, 0);
        s01 = __builtin_amdgcn_mfma_f32_16x16x32_bf16(aq0[c], bk1, s01, 0, 0, 0);
        s10 = __builtin_amdgcn_mfma_f32_16x16x32_bf16(aq1[c], bk0, s10, 0, 0, 0);
        s11 = __builtin_amdgcn_mfma_f32_16x16x32_bf16(aq1[c], bk1, s11, 0, 0, 0);
      }
    }
    float a0r[4], a1r[4];
#pragma unroll
    for (int r = 0; r < 4; ++r) {
      {  // row-set 0: row = mw + g*4 + r
        int row = mw + g * 4 + r;
        float v0 = ((n0 + lm) <= row) ? s00[r] : -1e30f;
        float v1 = ((n0 + 16 + lm) <= row) ? s01[r] : -1e30f;
        float mx = fmaxf(v0, v1);
#pragma unroll
        for (int off = 8; off > 0; off >>= 1) mx = fmaxf(mx, __shfl_xor(mx, off, 16));
        float mnew = fmaxf(m0r[r], mx);
        float alpha = __expf(m0r[r] - mnew);
        float p0 = __expf(v0 - mnew);
        float p1 = __expf(v1 - mnew);
        float rs = p0 + p1;
#pragma unroll
        for (int off = 8; off > 0; off >>= 1) rs += __shfl_xor(rs, off, 16);
        l0r[r] = l0r[r] * alpha + rs;
        m0r[r] = mnew; a0r[r] = alpha;
        Pw[(g * 4 + r) * 32 + lm] = f32_to_bf16(p0);
        Pw[(g * 4 + r) * 32 + 16 + lm] = f32_to_bf16(p1);
      }
      {  // row-set 1: row = mw + 16 + g*4 + r
        int row = mw + 16 + g * 4 + r;
        float v0 = ((n0 + lm) <= row) ? s10[r] : -1e30f;
        float v1 = ((n0 + 16 + lm) <= row) ? s11[r] : -1e30f;
        float mx = fmaxf(v0, v1);
#pragma unroll
        for (int off = 8; off > 0; off >>= 1) mx = fmaxf(mx, __shfl_xor(mx, off, 16));
        float mnew = fmaxf(m1r[r], mx);
        float alpha = __expf(m1r[r] - mnew);
        float p0 = __expf(v0 - mnew);
        float p1 = __expf(v1 - mnew);
        float rs = p0 + p1;
#pragma unroll
        for (int off = 8; off > 0; off >>= 1) rs += __shfl_xor(rs, off, 16);
        l1r[r] = l1r[r] * alpha + rs;
        m1r[r] = mnew; a1r[r] = alpha;
        Pw[(16 + g * 4 + r) * 32 + lm] = f32_to_bf16(p0);
        Pw[(16 + g * 4 + r) * 32 + 16 + lm] = f32_to_bf16(p1);
      }
    }
#pragma unroll
    for (int dc = 0; dc < 8; ++dc)
#pragma unroll
      for (int r = 0; r < 4; ++r) { o0[dc][r] *= a0r[r]; o1[dc][r] *= a1r[r]; }

    // wave-local LDS fence: writes above -> reads below (wave is lockstep)
    asm volatile("s_waitcnt lgkmcnt(0)" ::: "memory");

    short8 ap0 = *(const short8*)(Pw + lm * 32 + g * 8);
    short8 ap1 = *(const short8*)(Pw + (16 + lm) * 32 + g * 8);
    const uint16_t* vp = vt + (size_t)(h * HEADD + lm) * SEQ + n0 + g * 8;
#pragma unroll
    for (int dc = 0; dc < 8; ++dc) {
      short8 bv = *(const short8*)(vp + (size_t)(dc * 16) * SEQ);
      o0[dc] = __builtin_amdgcn_mfma_f32_16x16x32_bf16(ap0, bv, o0[dc], 0, 0, 0);
      o1[dc] = __builtin_amdgcn_mfma_f32_16x16x32_bf16(ap1, bv, o1[dc], 0, 0, 0);
    }
  }

#pragma unroll
  for (int dc = 0; dc < 8; ++dc)
#pragma unroll
    for (int r = 0; r < 4; ++r) {
      int row0 = mw + g * 4 + r;
      int row1 = mw + 16 + g * 4 + r;
      attn_out[(size_t)row0 * (NHEAD * HEADD) + h * HEADD + dc * 16 + lm] =
          f32_to_bf16(o0[dc][r] / l0r[r]);
      attn_out[(size_t)row1 * (NHEAD * HEADD) + h * HEADD + dc * 16 + lm] =
          f32_to_bf16(o1[dc][r] / l1r[r]);
    }
}

// ---------------- launch ----------------
extern "C" void kernel_launch(void* const* d_in, const int* in_sizes, int n_in,
                              void* d_out, int out_size, void* d_ws, size_t ws_size,
                              hipStream_t stream) {
  const float* x       = (const float*)d_in[0];
  const float* cosT    = (const float*)d_in[1];
  const float* sinT    = (const float*)d_in[2];
  const float* q_a_w   = (const float*)d_in[3];
  const float* q_a_nw  = (const float*)d_in[4];
  const float* q_b_w   = (const float*)d_in[5];
  const float* kv_a_w  = (const float*)d_in[6];
  const float* kv_a_nw = (const float*)d_in[7];
  const float* kv_b_w  = (const float*)d_in[8];
  const float* o_w     = (const float*)d_in[9];
  float* out = (float*)d_out;
  (void)in_sizes; (void)n_in; (void)out_size; (void)ws_size;

  char* base = (char*)d_ws;
  size_t off = 0;
  auto alloc = [&](size_t bytes) -> void* {
    void* r = base + off;
    off += (bytes + 255) & ~(size_t)255;
    return r;
  };
  uint16_t* x_bf      = (uint16_t*)alloc((size_t)SEQ * HIDDIM * 2);   // reused: attn_bf
  uint16_t* kv_raw    = (uint16_t*)alloc((size_t)SEQ * KVPAD * 2);
  uint16_t* kv_lat_bf = (uint16_t*)alloc((size_t)SEQ * KVRANK * 2);
  uint16_t* big       = (uint16_t*)alloc((size_t)SEQ * KVUPD * 2);    // kv_up_bf, later q_raw
  uint16_t* q_a_out   = (uint16_t*)alloc((size_t)SEQ * QRANK * 2);
  uint16_t* q_lat_bf  = (uint16_t*)alloc((size_t)SEQ * QRANK * 2);
  uint16_t* q_full    = (uint16_t*)alloc((size_t)NHEAD * SEQ * DQK * 2);
  uint16_t* k_full    = (uint16_t*)alloc((size_t)NHEAD * SEQ * DQK * 2);
  uint16_t* vt        = (uint16_t*)alloc((size_t)NHEAD * SEQ * HEADD * 2);
  uint16_t* attn_bf   = x_bf;  // alias: x_bf dead after q_a gemm

  // x -> bf16
  conv_f32_bf16<<<2048, 256, 0, stream>>>(x, x_bf, (size_t)SEQ * HIDDIM);

  // kv path
  gemm_bt<uint16_t><<<dim3(KVPAD / 128, SEQ / 128), 256, 0, stream>>>(
      x_bf, kv_a_w, kv_raw, SEQ, KVPAD, KVRANK + ROPED, HIDDIM);
  rmsnorm_bf16<<<SEQ, 256, 0, stream>>>(kv_raw, kv_a_nw, kv_lat_bf, KVRANK, KVPAD);
  gemm_bt<uint16_t><<<dim3(KVUPD / 128, SEQ / 128), 256, 0, stream>>>(
      kv_lat_bf, kv_b_w, big, SEQ, KVUPD, KVUPD, KVRANK);
  build_k_kernel<<<dim3(SEQ, NHEAD), DQK, 0, stream>>>(kv_raw, big, cosT, sinT, k_full);
  transpose_v<<<dim3(SEQ / 64, NHEAD), 256, 0, stream>>>(big, vt);

  // q path
  gemm_bt<uint16_t><<<dim3(QRANK / 128, SEQ / 128), 256, 0, stream>>>(
      x_bf, q_a_w, q_a_out, SEQ, QRANK, QRANK, HIDDIM);
  rmsnorm_bf16<<<SEQ, 256, 0, stream>>>(q_a_out, q_a_nw, q_lat_bf, QRANK, QRANK);
  gemm_bt<uint16_t><<<dim3(QDIM / 128, SEQ / 128), 256, 0, stream>>>(
      q_lat_bf, q_b_w, big, SEQ, QDIM, QDIM, QRANK);   // big reused as q_raw
  build_q_kernel<<<dim3(SEQ, NHEAD), DQK, 0, stream>>>(big, cosT, sinT, q_full);

  // attention (writes attn_bf == x_bf region; x_bf no longer needed)
  attn_kernel<<<dim3(SEQ / 128, NHEAD), 256, 0, stream>>>(q_full, k_full, vt, attn_bf);

  // output projection -> d_out (fp32)
  gemm_bt<float><<<dim3(HIDDIM / 128, SEQ / 128), 256, 0, stream>>>(
      attn_bf, o_w, out, SEQ, HIDDIM, HIDDIM, HIDDIM);
}

// Round 4
// 891.740 us; speedup vs baseline: 1.4983x; 1.3326x over previous
//
#include <hip/hip_runtime.h>
#include <stdint.h>

typedef __attribute__((ext_vector_type(8))) short short8;
typedef __attribute__((ext_vector_type(4))) short bf16x4;
typedef __attribute__((ext_vector_type(4))) float f32x4;

#define SEQ     2048
#define HIDDIM  4096
#define NHEAD   32
#define HEADD   128
#define ROPED   64
#define QRANK   1536
#define KVRANK  896
#define DQK     192          // ROPED + HEADD
#define KVPAD   1024         // padded (KVRANK+ROPED)=960 -> 1024
#define QDIM    6144         // NHEAD*DQK
#define KVUPD   8192         // NHEAD*2*HEADD
#define RMS_EPS 1e-6f
#define ATT_SCALE 0.07216878364870322f  // 192^-0.5

static __device__ __forceinline__ uint16_t f32_to_bf16(float f) {
  union { float f; uint32_t u; } v; v.f = f;
  uint32_t u = v.u;
  u += 0x7FFFu + ((u >> 16) & 1u);   // round-to-nearest-even
  return (uint16_t)(u >> 16);
}
static __device__ __forceinline__ float bf16_to_f32(uint16_t h) {
  union { uint32_t u; float f; } v; v.u = ((uint32_t)h) << 16;
  return v.f;
}

// global -> LDS direct (16B per lane; LDS dest = wave-uniform base + lane*16)
#define GLDS16(gp, lp)                                                              \
  __builtin_amdgcn_global_load_lds((const __attribute__((address_space(1))) void*)(gp), \
                                   (__attribute__((address_space(3))) void*)(lp), 16, 0, 0)

// ---------------- packed converts (fp32 -> bf16 pairs) ----------------
__global__ void conv_pk(const float* __restrict__ in, uint32_t* __restrict__ out, size_t npairs) {
  size_t i = blockIdx.x * (size_t)blockDim.x + threadIdx.x;
  size_t stride = (size_t)gridDim.x * blockDim.x;
  for (; i < npairs; i += stride) {
    float a = in[2 * i], b = in[2 * i + 1];
    out[i] = (uint32_t)f32_to_bf16(a) | ((uint32_t)f32_to_bf16(b) << 16);
  }
}
__global__ void conv_pad_pk(const float* __restrict__ in, uint32_t* __restrict__ out,
                            size_t npairs_in, size_t npairs_out) {
  size_t i = blockIdx.x * (size_t)blockDim.x + threadIdx.x;
  size_t stride = (size_t)gridDim.x * blockDim.x;
  for (; i < npairs_out; i += stride) {
    uint32_t v = 0;
    if (i < npairs_in) {
      float a = in[2 * i], b = in[2 * i + 1];
      v = (uint32_t)f32_to_bf16(a) | ((uint32_t)f32_to_bf16(b) << 16);
    }
    out[i] = v;
  }
}

// ---------------- RMSNorm (bf16 in -> bf16 out) ----------------
__global__ void rmsnorm_bf16(const uint16_t* __restrict__ in, const float* __restrict__ w,
                             uint16_t* __restrict__ out, int C, int ldin) {
  int s = blockIdx.x;
  const uint16_t* row = in + (size_t)s * ldin;
  float ss = 0.f;
  for (int c = threadIdx.x; c < C; c += blockDim.x) { float v = bf16_to_f32(row[c]); ss += v * v; }
#pragma unroll
  for (int off = 32; off > 0; off >>= 1) ss += __shfl_down(ss, off, 64);
  __shared__ float red[4];
  int wid = threadIdx.x >> 6;
  if ((threadIdx.x & 63) == 0) red[wid] = ss;
  __syncthreads();
  float total = red[0] + red[1] + red[2] + red[3];
  float scale = rsqrtf(total / (float)C + RMS_EPS);
  for (int c = threadIdx.x; c < C; c += blockDim.x)
    out[(size_t)s * C + c] = f32_to_bf16(bf16_to_f32(row[c]) * scale * w[c]);
}

// ---------------- GEMM (m97-style): C(M,N) = A(M,K)bf16 @ B(N,K)^T bf16 ----------------
// global_load_lds width-16 staging for both A and B. M,N %128==0, K%32==0.
template <typename CT>
__global__ __launch_bounds__(256) void gemm_lds(const uint16_t* __restrict__ A,
                                                const uint16_t* __restrict__ B,
                                                CT* __restrict__ C,
                                                int M, int N, int K) {
  __shared__ __align__(16) uint16_t As[128 * 32];
  __shared__ __align__(16) uint16_t Bs[128 * 32];
  const int t = threadIdx.x;
  const int m0 = blockIdx.y * 128, n0 = blockIdx.x * 128;
  const int w = t >> 6, l = t & 63;
  const int rb = (w >> 1) * 64, cb = (w & 1) * 64;
  const int g = l >> 4, lm = l & 15;
  const int srow = l >> 2;         // 0..15 within a 16-row wave slab
  const int scol = (l & 3) * 8;    // 0,8,16,24

  f32x4 acc[4][4];
#pragma unroll
  for (int i = 0; i < 4; ++i)
#pragma unroll
    for (int j = 0; j < 4; ++j) acc[i][j] = (f32x4){0.f, 0.f, 0.f, 0.f};

  const uint16_t* Abase = A + (size_t)m0 * K;
  const uint16_t* Bbase = B + (size_t)n0 * K;

  for (int k0 = 0; k0 < K; k0 += 32) {
    __syncthreads();
#pragma unroll
    for (int c = 0; c < 2; ++c) {
      int rowa = c * 64 + w * 16;                 // wave-uniform slab start
      GLDS16(Abase + (size_t)(rowa + srow) * K + k0 + scol, As + rowa * 32);
      GLDS16(Bbase + (size_t)(rowa + srow) * K + k0 + scol, Bs + rowa * 32);
    }
    __syncthreads();
    short8 af[4], bfr[4];
#pragma unroll
    for (int i = 0; i < 4; ++i)
      af[i] = *(const short8*)(As + (rb + i * 16 + lm) * 32 + g * 8);
#pragma unroll
    for (int j = 0; j < 4; ++j)
      bfr[j] = *(const short8*)(Bs + (cb + j * 16 + lm) * 32 + g * 8);
#pragma unroll
    for (int i = 0; i < 4; ++i)
#pragma unroll
      for (int j = 0; j < 4; ++j)
        acc[i][j] = __builtin_amdgcn_mfma_f32_16x16x32_bf16(af[i], bfr[j], acc[i][j], 0, 0, 0);
  }

#pragma unroll
  for (int i = 0; i < 4; ++i)
#pragma unroll
    for (int j = 0; j < 4; ++j)
#pragma unroll
      for (int r = 0; r < 4; ++r) {
        int row = m0 + rb + i * 16 + g * 4 + r;
        int col = n0 + cb + j * 16 + lm;
        float v = acc[i][j][r];
        if constexpr (sizeof(CT) == 4) C[(size_t)row * N + col] = v;
        else                           C[(size_t)row * N + col] = (CT)f32_to_bf16(v);
      }
}

// ---------------- build q_full[h][s][192] (rope + scale, bf16) ----------------
__global__ void build_q_kernel(const uint16_t* __restrict__ qraw, const float* __restrict__ cosT,
                               const float* __restrict__ sinT, uint16_t* __restrict__ qf) {
  int s = blockIdx.x, h = blockIdx.y, d = threadIdx.x;  // d in [0,192)
  const uint16_t* base = qraw + (size_t)s * QDIM + h * DQK;
  float val;
  if (d < ROPED) {
    float c = cosT[s * ROPED + d], sn = sinT[s * ROPED + d];
    float x = bf16_to_f32(base[d]);
    float other = (d < 32) ? -bf16_to_f32(base[d + 32]) : bf16_to_f32(base[d - 32]);
    val = x * c + other * sn;
  } else {
    val = bf16_to_f32(base[d]);
  }
  qf[((size_t)(h * SEQ + s)) * DQK + d] = f32_to_bf16(val * ATT_SCALE);
}

// ---------------- build k_full[h][s][192] ----------------
__global__ void build_k_kernel(const uint16_t* __restrict__ kvraw, const uint16_t* __restrict__ kvup,
                               const float* __restrict__ cosT, const float* __restrict__ sinT,
                               uint16_t* __restrict__ kf) {
  int s = blockIdx.x, h = blockIdx.y, d = threadIdx.x;
  float val;
  if (d < ROPED) {
    float c = cosT[s * ROPED + d], sn = sinT[s * ROPED + d];
    const uint16_t* base = kvraw + (size_t)s * KVPAD + KVRANK;
    float x = bf16_to_f32(base[d]);
    float other = (d < 32) ? -bf16_to_f32(base[d + 32]) : bf16_to_f32(base[d - 32]);
    val = x * c + other * sn;
  } else {
    val = bf16_to_f32(kvup[(size_t)s * KVUPD + h * 256 + (d - ROPED)]);
  }
  kf[((size_t)(h * SEQ + s)) * DQK + d] = f32_to_bf16(val);
}

// ---------------- transpose V: kvup[s][h*256+128+d] -> vt[h][d][s] ----------------
typedef __attribute__((ext_vector_type(8))) unsigned short ushort8;
__global__ __launch_bounds__(256) void transpose_v(const uint16_t* __restrict__ kvup,
                                                   uint16_t* __restrict__ vt) {
  __shared__ uint16_t tile[64][136];
  const int s0 = blockIdx.x * 64, h = blockIdx.y, t = threadIdx.x;
  {
    int sl = t >> 2;
    int dch = (t & 3) * 32;
    const uint16_t* src = kvup + (size_t)(s0 + sl) * KVUPD + h * 256 + HEADD + dch;
#pragma unroll
    for (int j = 0; j < 32; j += 8)
      *(ushort8*)&tile[sl][dch + j] = *(const ushort8*)(src + j);
  }
  __syncthreads();
  {
    int d = t >> 1;
    int sch = (t & 1) * 32;
    uint16_t buf[32];
#pragma unroll
    for (int j = 0; j < 32; ++j) buf[j] = tile[sch + j][d];
    uint16_t* dst = vt + ((size_t)(h * HEADD) + d) * SEQ + s0 + sch;
#pragma unroll
    for (int j = 0; j < 32; j += 8) *(ushort8*)(dst + j) = *(ushort8*)(buf + j);
  }
}

// ---------------- flash attention (S^T trick; P stays in registers) ----------------
// grid (SEQ/128, NHEAD), 256 threads = 4 waves, 32 q-rows per wave.
// Causal balance: waves 0,1 -> chunk bx; waves 2,3 -> chunk 31-bx (64-row chunks).
__global__ __launch_bounds__(256) void attn_kernel(const uint16_t* __restrict__ qf,
                                                   const uint16_t* __restrict__ kf,
                                                   const uint16_t* __restrict__ vt,
                                                   uint16_t* __restrict__ attn_out) {
  const int h = blockIdx.y;
  const int w = threadIdx.x >> 6;
  const int l = threadIdx.x & 63;
  const int g = l >> 4, lm = l & 15;
  const int chunk = (w < 2) ? blockIdx.x : (31 - blockIdx.x);
  const int mw = chunk * 64 + (w & 1) * 32;

  // Q fragments (scale folded in). Same data serves as B-operand of S^T MFMA.
  const uint16_t* q0 = qf + ((size_t)(h * SEQ + mw + lm)) * DQK;
  const uint16_t* q1 = qf + ((size_t)(h * SEQ + mw + 16 + lm)) * DQK;
  short8 aq0[6], aq1[6];
#pragma unroll
  for (int c = 0; c < 6; ++c) {
    aq0[c] = *(const short8*)(q0 + c * 32 + g * 8);
    aq1[c] = *(const short8*)(q1 + c * 32 + g * 8);
  }

  f32x4 o0[8], o1[8];
#pragma unroll
  for (int dc = 0; dc < 8; ++dc) { o0[dc] = (f32x4){0,0,0,0}; o1[dc] = (f32x4){0,0,0,0}; }
  float m_q0 = -1e30f, l_q0 = 0.f, m_q1 = -1e30f, l_q1 = 0.f;
  const int q0i = mw + lm, q1i = mw + 16 + lm;

  for (int n0 = 0; n0 <= mw; n0 += 32) {
    // S^T tiles: sT[kh][qs][r] = S[key=n0+kh*16+g*4+r][query=mw+qs*16+lm]
    f32x4 sk0q0 = (f32x4){0,0,0,0}, sk1q0 = (f32x4){0,0,0,0};
    f32x4 sk0q1 = (f32x4){0,0,0,0}, sk1q1 = (f32x4){0,0,0,0};
    {
      const uint16_t* k0p = kf + ((size_t)(h * SEQ + n0 + lm)) * DQK + g * 8;
      const uint16_t* k1p = kf + ((size_t)(h * SEQ + n0 + 16 + lm)) * DQK + g * 8;
#pragma unroll
      for (int c = 0; c < 6; ++c) {
        short8 bk0 = *(const short8*)(k0p + c * 32);
        short8 bk1 = *(const short8*)(k1p + c * 32);
        sk0q0 = __builtin_amdgcn_mfma_f32_16x16x32_bf16(bk0, aq0[c], sk0q0, 0, 0, 0);
        sk1q0 = __builtin_amdgcn_mfma_f32_16x16x32_bf16(bk1, aq0[c], sk1q0, 0, 0, 0);
        sk0q1 = __builtin_amdgcn_mfma_f32_16x16x32_bf16(bk0, aq1[c], sk0q1, 0, 0, 0);
        sk1q1 = __builtin_amdgcn_mfma_f32_16x16x32_bf16(bk1, aq1[c], sk1q1, 0, 0, 0);
      }
    }
    const int kb0 = n0 + g * 4, kb1 = n0 + 16 + g * 4;

    // ---- softmax qs=0 (query q0i) ----
    float alpha0, alpha1;
    bf16x4 ap00, ap01, ap10, ap11;
    {
      float v0[4], v1[4];
#pragma unroll
      for (int r = 0; r < 4; ++r) {
        v0[r] = (kb0 + r <= q0i) ? sk0q0[r] : -1e30f;
        v1[r] = (kb1 + r <= q0i) ? sk1q0[r] : -1e30f;
      }
      float mx = fmaxf(fmaxf(fmaxf(v0[0], v0[1]), fmaxf(v0[2], v0[3])),
                       fmaxf(fmaxf(v1[0], v1[1]), fmaxf(v1[2], v1[3])));
      mx = fmaxf(mx, __shfl_xor(mx, 16, 64));
      mx = fmaxf(mx, __shfl_xor(mx, 32, 64));
      float mnew = fmaxf(m_q0, mx);
      alpha0 = __expf(m_q0 - mnew);
      float rs = 0.f;
#pragma unroll
      for (int r = 0; r < 4; ++r) {
        float p0 = __expf(v0[r] - mnew), p1 = __expf(v1[r] - mnew);
        rs += p0 + p1;
        ap00[r] = (short)f32_to_bf16(p0);
        ap01[r] = (short)f32_to_bf16(p1);
      }
      rs += __shfl_xor(rs, 16, 64);
      rs += __shfl_xor(rs, 32, 64);
      l_q0 = l_q0 * alpha0 + rs;
      m_q0 = mnew;
    }
    // ---- softmax qs=1 (query q1i) ----
    {
      float v0[4], v1[4];
#pragma unroll
      for (int r = 0; r < 4; ++r) {
        v0[r] = (kb0 + r <= q1i) ? sk0q1[r] : -1e30f;
        v1[r] = (kb1 + r <= q1i) ? sk1q1[r] : -1e30f;
      }
      float mx = fmaxf(fmaxf(fmaxf(v0[0], v0[1]), fmaxf(v0[2], v0[3])),
                       fmaxf(fmaxf(v1[0], v1[1]), fmaxf(v1[2], v1[3])));
      mx = fmaxf(mx, __shfl_xor(mx, 16, 64));
      mx = fmaxf(mx, __shfl_xor(mx, 32, 64));
      float mnew = fmaxf(m_q1, mx);
      alpha1 = __expf(m_q1 - mnew);
      float rs = 0.f;
#pragma unroll
      for (int r = 0; r < 4; ++r) {
        float p0 = __expf(v0[r] - mnew), p1 = __expf(v1[r] - mnew);
        rs += p0 + p1;
        ap10[r] = (short)f32_to_bf16(p0);
        ap11[r] = (short)f32_to_bf16(p1);
      }
      rs += __shfl_xor(rs, 16, 64);
      rs += __shfl_xor(rs, 32, 64);
      l_q1 = l_q1 * alpha1 + rs;
      m_q1 = mnew;
    }

    // broadcast alphas from query-column domain (lm) to o-row domain (g*4+r)
    float a0b[4], a1b[4];
#pragma unroll
    for (int r = 0; r < 4; ++r) {
      int src = (l & 48) | (g * 4 + r);
      a0b[r] = __shfl(alpha0, src, 64);
      a1b[r] = __shfl(alpha1, src, 64);
    }
#pragma unroll
    for (int dc = 0; dc < 8; ++dc)
#pragma unroll
      for (int r = 0; r < 4; ++r) { o0[dc][r] *= a0b[r]; o1[dc][r] *= a1b[r]; }

    // PV: O += P^T-as-A @ V  (16x16x16, P stays in registers)
    const uint16_t* vp = vt + (size_t)(h * HEADD + lm) * SEQ + n0 + g * 4;
#pragma unroll
    for (int dc = 0; dc < 8; ++dc) {
      bf16x4 bv0 = *(const bf16x4*)(vp + (size_t)(dc * 16) * SEQ);
      bf16x4 bv1 = *(const bf16x4*)(vp + (size_t)(dc * 16) * SEQ + 16);
      o0[dc] = __builtin_amdgcn_mfma_f32_16x16x16bf16_1k(ap00, bv0, o0[dc], 0, 0, 0);
      o0[dc] = __builtin_amdgcn_mfma_f32_16x16x16bf16_1k(ap01, bv1, o0[dc], 0, 0, 0);
      o1[dc] = __builtin_amdgcn_mfma_f32_16x16x16bf16_1k(ap10, bv0, o1[dc], 0, 0, 0);
      o1[dc] = __builtin_amdgcn_mfma_f32_16x16x16bf16_1k(ap11, bv1, o1[dc], 0, 0, 0);
    }
  }

  // epilogue: broadcast l to row domain, normalize, store
  float l0b[4], l1b[4];
#pragma unroll
  for (int r = 0; r < 4; ++r) {
    int src = (l & 48) | (g * 4 + r);
    l0b[r] = __shfl(l_q0, src, 64);
    l1b[r] = __shfl(l_q1, src, 64);
  }
#pragma unroll
  for (int dc = 0; dc < 8; ++dc)
#pragma unroll
    for (int r = 0; r < 4; ++r) {
      int row0 = mw + g * 4 + r;
      int row1 = mw + 16 + g * 4 + r;
      attn_out[(size_t)row0 * (NHEAD * HEADD) + h * HEADD + dc * 16 + lm] =
          f32_to_bf16(o0[dc][r] / l0b[r]);
      attn_out[(size_t)row1 * (NHEAD * HEADD) + h * HEADD + dc * 16 + lm] =
          f32_to_bf16(o1[dc][r] / l1b[r]);
    }
}

// ---------------- launch ----------------
extern "C" void kernel_launch(void* const* d_in, const int* in_sizes, int n_in,
                              void* d_out, int out_size, void* d_ws, size_t ws_size,
                              hipStream_t stream) {
  const float* x       = (const float*)d_in[0];
  const float* cosT    = (const float*)d_in[1];
  const float* sinT    = (const float*)d_in[2];
  const float* q_a_w   = (const float*)d_in[3];
  const float* q_a_nw  = (const float*)d_in[4];
  const float* q_b_w   = (const float*)d_in[5];
  const float* kv_a_w  = (const float*)d_in[6];
  const float* kv_a_nw = (const float*)d_in[7];
  const float* kv_b_w  = (const float*)d_in[8];
  const float* o_w     = (const float*)d_in[9];
  float* out = (float*)d_out;
  (void)in_sizes; (void)n_in; (void)out_size; (void)ws_size;

  char* base = (char*)d_ws;
  size_t off = 0;
  auto alloc = [&](size_t bytes) -> void* {
    void* r = base + off;
    off += (bytes + 255) & ~(size_t)255;
    return r;
  };
  uint16_t* x_bf      = (uint16_t*)alloc((size_t)SEQ * HIDDIM * 2);   // reused: attn_bf
  uint16_t* kv_raw    = (uint16_t*)alloc((size_t)SEQ * KVPAD * 2);
  uint16_t* kv_lat_bf = (uint16_t*)alloc((size_t)SEQ * KVRANK * 2);
  uint16_t* big       = (uint16_t*)alloc((size_t)SEQ * KVUPD * 2);    // kv_up_bf, later q_raw
  uint16_t* q_a_out   = (uint16_t*)alloc((size_t)SEQ * QRANK * 2);
  uint16_t* q_lat_bf  = (uint16_t*)alloc((size_t)SEQ * QRANK * 2);
  uint16_t* q_full    = (uint16_t*)alloc((size_t)NHEAD * SEQ * DQK * 2);
  uint16_t* k_full    = (uint16_t*)alloc((size_t)NHEAD * SEQ * DQK * 2);
  uint16_t* vt        = (uint16_t*)alloc((size_t)NHEAD * SEQ * HEADD * 2);
  uint16_t* wscr      = (uint16_t*)alloc((size_t)HIDDIM * HIDDIM * 2);  // bf16 weight scratch (33.6MB)
  uint16_t* attn_bf   = x_bf;  // alias: x_bf dead after q_a gemm

  // x -> bf16
  conv_pk<<<1024, 256, 0, stream>>>(x, (uint32_t*)x_bf, (size_t)SEQ * HIDDIM / 2);

  // ---- kv path ----
  conv_pad_pk<<<1024, 256, 0, stream>>>(kv_a_w, (uint32_t*)wscr,
                                        (size_t)(KVRANK + ROPED) * HIDDIM / 2,
                                        (size_t)KVPAD * HIDDIM / 2);
  gemm_lds<uint16_t><<<dim3(KVPAD / 128, SEQ / 128), 256, 0, stream>>>(
      x_bf, wscr, kv_raw, SEQ, KVPAD, HIDDIM);
  rmsnorm_bf16<<<SEQ, 256, 0, stream>>>(kv_raw, kv_a_nw, kv_lat_bf, KVRANK, KVPAD);
  conv_pk<<<1024, 256, 0, stream>>>(kv_b_w, (uint32_t*)wscr, (size_t)KVUPD * KVRANK / 2);
  gemm_lds<uint16_t><<<dim3(KVUPD / 128, SEQ / 128), 256, 0, stream>>>(
      kv_lat_bf, wscr, big, SEQ, KVUPD, KVRANK);
  build_k_kernel<<<dim3(SEQ, NHEAD), DQK, 0, stream>>>(kv_raw, big, cosT, sinT, k_full);
  transpose_v<<<dim3(SEQ / 64, NHEAD), 256, 0, stream>>>(big, vt);

  // ---- q path ----
  conv_pk<<<1024, 256, 0, stream>>>(q_a_w, (uint32_t*)wscr, (size_t)QRANK * HIDDIM / 2);
  gemm_lds<uint16_t><<<dim3(QRANK / 128, SEQ / 128), 256, 0, stream>>>(
      x_bf, wscr, q_a_out, SEQ, QRANK, HIDDIM);
  rmsnorm_bf16<<<SEQ, 256, 0, stream>>>(q_a_out, q_a_nw, q_lat_bf, QRANK, QRANK);
  conv_pk<<<1024, 256, 0, stream>>>(q_b_w, (uint32_t*)wscr, (size_t)QDIM * QRANK / 2);
  gemm_lds<uint16_t><<<dim3(QDIM / 128, SEQ / 128), 256, 0, stream>>>(
      q_lat_bf, wscr, big, SEQ, QDIM, QRANK);   // big reused as q_raw
  build_q_kernel<<<dim3(SEQ, NHEAD), DQK, 0, stream>>>(big, cosT, sinT, q_full);

  // ---- attention (writes attn_bf == x_bf region) ----
  attn_kernel<<<dim3(SEQ / 128, NHEAD), 256, 0, stream>>>(q_full, k_full, vt, attn_bf);

  // ---- output projection -> d_out (fp32) ----
  conv_pk<<<1024, 256, 0, stream>>>(o_w, (uint32_t*)wscr, (size_t)HIDDIM * HIDDIM / 2);
  gemm_lds<float><<<dim3(HIDDIM / 128, SEQ / 128), 256, 0, stream>>>(
      attn_bf, wscr, out, SEQ, HIDDIM, HIDDIM);
}